// Round 9
// baseline (183.799 us; speedup 1.0000x reference)
//
#include <hip/hip_runtime.h>

// B=2, M=8192, H=8, D=64, hd=512, S=512, n_seg=16
// d_in: q(8388608 f32), k, v (unused), w_qkv(786432 f32), w_out(262144 f32)
// d_out: 8388608 f32

typedef short bfrag __attribute__((ext_vector_type(8)));   // 8 bf16 (4 VGPR)
typedef float ffrag __attribute__((ext_vector_type(4)));   // MFMA C/D
typedef short svec4 __attribute__((ext_vector_type(4)));
typedef unsigned uvec4 __attribute__((ext_vector_type(4)));

__device__ inline short f2bf(float x) {  // RNE
  unsigned u = __builtin_bit_cast(unsigned, x);
  u = (u + 0x7fffu + ((u >> 16) & 1u)) >> 16;
  return (short)u;
}
__device__ inline float fexp2(float x) {
#if __has_builtin(__builtin_amdgcn_exp2f)
  return __builtin_amdgcn_exp2f(x);   // v_exp_f32 (hw is base-2)
#else
  return __expf(x * 0.6931471805599453f);
#endif
}
__device__ inline unsigned cvtpk(float a, float b) {  // lo=bf16(a), hi=bf16(b)
  unsigned r;
  asm("v_cvt_pk_bf16_f32 %0, %1, %2" : "=v"(r) : "v"(a), "v"(b));
  return r;
}
__device__ inline void gload_lds16(const void* g, void* l) {
  __builtin_amdgcn_global_load_lds(
      (const __attribute__((address_space(1))) unsigned*)g,
      (__attribute__((address_space(3))) unsigned*)l, 16, 0, 0);
}

// Hilbert d->(x,y) on 128x128 (Wikipedia pair; reference forward is the
// s-flip variant which is bit-identical for d, see round-2 analysis).
__device__ inline int d2xy128(int d) {
  int x = 0, y = 0, t = d;
  for (int s = 1; s < 128; s <<= 1) {
    int rx = 1 & (t >> 1);
    int ry = 1 & (t ^ rx);
    if (ry == 0) {
      if (rx == 1) { x = s - 1 - x; y = s - 1 - y; }
      int tt = x; x = y; y = tt;
    }
    x += s * rx;
    y += s * ry;
    t >>= 2;
  }
  return y * 128 + x;
}

// ---------------- Kernel 1: head-mean + eff. weights + perm (closed form) ---
__global__ __launch_bounds__(256) void prep_kernel(
    const float* __restrict__ q, const float* __restrict__ w_qkv,
    const float* __restrict__ w_out, short* __restrict__ xmean,
    short* __restrict__ weff, short* __restrict__ woutb,
    int* __restrict__ perm) {
  int i = blockIdx.x * 256 + threadIdx.x;
  if (i < 1048576) {
    int bm = i >> 6, d = i & 63;
    const float* p = q + (size_t)bm * 512 + d;
    float s = 0.f;
#pragma unroll
    for (int h = 0; h < 8; ++h) s += p[h * 64];
    xmean[i] = f2bf(s * 0.125f);
  } else if (i < 1048576 + 98304) {
    int j = i - 1048576;
    int f = j >> 6;
    const float* p = w_qkv + (size_t)f * 512 + (j & 63);
    float s = 0.f;
#pragma unroll
    for (int r = 0; r < 8; ++r) s += p[r * 64];
    if (f < 512) s *= 0.125f * 1.44269504088896f;  // D^-0.5 * log2(e)
    weff[j] = f2bf(s);
  } else if (i < 1048576 + 98304 + 262144) {
    int j = i - 1048576 - 98304;
    woutb[j] = f2bf(w_out[j]);
  } else if (i < 1048576 + 98304 + 262144 + 8192) {
    int r = i - (1048576 + 98304 + 262144);
    perm[r] = d2xy128(r < 4096 ? r : r + 8192);
  }
}

// ---------------- Kernel 2: QKV projection into permuted/segment layouts ----
// v2: W-quarter (384x64 = 48KB) staged to LDS once per block via
// global_load_lds(16B) with unit XOR-swizzle (u^=row&7); Q/K results bounce
// through a per-wave padded [16][72] LDS tile and store 16B/lane.
// Qs[b][p][f'], Ks[b][p][f'] (rows = permuted positions); Vt[b][n][h][d][t]
__global__ __launch_bounds__(256, 2) void qkv_kernel(
    const short* __restrict__ xmean, const short* __restrict__ weff,
    const int* __restrict__ perm, short* __restrict__ Qs,
    short* __restrict__ Ks, short* __restrict__ Vt) {
  __shared__ short Wlds[384 * 64];       // 48 KB, unit-swizzled rows of 128B
  __shared__ short Sb[4][2][16 * 72];    // per-wave dbuf bounce, 18 KB
  int tid = threadIdx.x;
  int w = tid >> 6, lane = tid & 63;
  int ml = lane & 15, quad = lane >> 4;
  int rg = blockIdx.x >> 2, fq = blockIdx.x & 3;
  int r0 = rg * 64 + w * 16;  // 16 permuted rows per wave
  int r = r0 + ml;
  int b = r >> 13, p = r & 8191;
  int src = (b << 13) + perm[p];
  bfrag a0 = *(const bfrag*)(xmean + (size_t)src * 64 + quad * 8);
  bfrag a1 = *(const bfrag*)(xmean + (size_t)src * 64 + 32 + quad * 8);
  int p0 = r0 & 8191;
  int bq = r0 >> 13;
  int nseg = p0 >> 9;
  int sbase = (p0 & 511) + quad * 4;

  // stage W quarter: wave w rows [w*96, w*96+96), 12 x 1KB instrs.
  {
    int lrow = lane >> 3;  // 0..7 within the 8-row chunk
    int lu = lane & 7;
    const short* wsrc = weff + (size_t)(fq * 384 + w * 96 + lrow) * 64 +
                        ((lu ^ (lrow & 7)) * 8);
#pragma unroll
    for (int i = 0; i < 12; ++i)
      gload_lds16(wsrc + (size_t)i * 8 * 64,
                  (char*)Wlds + w * 12288 + i * 1024);
  }
  __syncthreads();

#pragma unroll 1
  for (int gg = 0; gg < 6; ++gg) {
    int nt0 = fq * 24 + gg * 4;
    int f0g = nt0 * 16;
    short* sb = &Sb[w][gg & 1][0];
    if (f0g < 1024) {
      // Q/K group: 4 tiles -> bounce -> 2 coalesced 16B/lane stores
#pragma unroll
      for (int t = 0; t < 4; ++t) {
        int row = (gg * 4 + t) * 16 + ml;  // local W row
        const char* Wb = (const char*)Wlds + row * 128;
        int sw = (row & 7) << 4;
        bfrag wf0 = *(const bfrag*)(Wb + ((quad << 4) ^ sw));
        bfrag wf1 = *(const bfrag*)(Wb + (((4 + quad) << 4) ^ sw));
        ffrag acc = {0.f, 0.f, 0.f, 0.f};
        // D[f][row]: lane ml = row(pos), quad*4+g = f
        acc = __builtin_amdgcn_mfma_f32_16x16x32_bf16(wf0, a0, acc, 0, 0, 0);
        acc = __builtin_amdgcn_mfma_f32_16x16x32_bf16(wf1, a1, acc, 0, 0, 0);
        svec4 pk;
#pragma unroll
        for (int g = 0; g < 4; ++g) pk[g] = f2bf(acc[g]);
        *(svec4*)((char*)sb + ml * 144 + t * 32 + quad * 8) = pk;
      }
      __builtin_amdgcn_sched_barrier(0);  // keep reads after writes
      int rrow = lane >> 3;
      int cu = lane & 7;
      bfrag v0 = *(const bfrag*)((char*)sb + rrow * 144 + cu * 16);
      bfrag v1 = *(const bfrag*)((char*)sb + (rrow + 8) * 144 + cu * 16);
      short* dst = (f0g < 512) ? Qs : Ks;
      int fo = f0g & 511;
      *(bfrag*)(dst + (size_t)(r0 + rrow) * 512 + fo + cu * 8) = v0;
      *(bfrag*)(dst + (size_t)(r0 + rrow + 8) * 512 + fo + cu * 8) = v1;
    } else {
      // V group: D[row][f] orientation, direct svec4 stores into Vt
#pragma unroll
      for (int t = 0; t < 4; ++t) {
        int nt = nt0 + t;
        int row = (gg * 4 + t) * 16 + ml;
        const char* Wb = (const char*)Wlds + row * 128;
        int sw = (row & 7) << 4;
        bfrag wf0 = *(const bfrag*)(Wb + ((quad << 4) ^ sw));
        bfrag wf1 = *(const bfrag*)(Wb + (((4 + quad) << 4) ^ sw));
        ffrag acc = {0.f, 0.f, 0.f, 0.f};
        acc = __builtin_amdgcn_mfma_f32_16x16x32_bf16(a0, wf0, acc, 0, 0, 0);
        acc = __builtin_amdgcn_mfma_f32_16x16x32_bf16(a1, wf1, acc, 0, 0, 0);
        int fl = nt * 16 + ml - 1024;
        int hh = fl >> 6, dd = fl & 63;
        svec4 pk;
#pragma unroll
        for (int g = 0; g < 4; ++g) pk[g] = f2bf(acc[g]);
        *(svec4*)(Vt + ((((size_t)bq * 16 + nseg) * 8 + hh) * 64 + dd) * 512 +
                  sbase) = pk;
      }
    }
  }
}

// ---------------- Kernel 3: segment attention, no-max softmax, S^T=K·Q^T ----
// v6: nq=4 + permlane. v5 post-mortem: permlane transpose worked (attn
// ~33us, conflicts->0 expected), but DS-pipe budget shows the next limit:
// all waves of a block read IDENTICAL K/V fragments from LDS, so DS issue
// scales with wave count (nq=2: 4096 waves x 16 b128/tile ~ 10us/CU) and
// K/V staging is 4x-redundant (4 qq-siblings). Now 64 q/wave (nq=4, 512
// blocks, qq in {0,1}): total DS instrs halve (~5us), MFMA:DS ratio per
// wave doubles (64:16), staging redundancy halves. This is the verified R6
// structure composed with the verified permlane transpose; R6's 42.7us had
// the bpermute LDS round-trip in-chain, which permlane removed -> 2
// waves/SIMD now covers a much shorter chain. VGPR demand ~156 < 256 cap
// (launch_bounds(256,2)); accumulators pin 96 so sink can't collapse it.
__global__ __launch_bounds__(256, 2) void attn_kernel(
    const short* __restrict__ Qs, const short* __restrict__ Ks,
    const short* __restrict__ Vt, const int* __restrict__ perm,
    short* __restrict__ aout) {
  __shared__ short Klds[2][64 * 64];
  __shared__ short Vlds[2][64 * 64];
  int tid = threadIdx.x;
  int w = tid >> 6, lane = tid & 63;
  int ml = lane & 15, quad = lane >> 4;
  int sh = blockIdx.x & 255;
  int qq = blockIdx.x >> 8;  // 0..1
  int b = sh >> 7;
  int n = (sh >> 3) & 15;
  int h = sh & 7;
  size_t segrow = (size_t)(b * 8192 + n * 512);
  const short* Qseg = Qs + segrow * 512 + h * 64;
  const short* Kseg = Ks + segrow * 512 + h * 64;
  const short* Vseg = Vt + (((size_t)(b * 16 + n) * 8 + h) * 64) * 512;
  int q0 = qq * 256 + w * 64;  // 64 q-cols per wave (4 chains)
  bfrag qa[4][2];
#pragma unroll
  for (int nq = 0; nq < 4; ++nq)
#pragma unroll
    for (int ks = 0; ks < 2; ++ks)
      qa[nq][ks] = *(const bfrag*)(Qseg + (size_t)(q0 + nq * 16 + ml) * 512 +
                                   ks * 32 + quad * 8);
  ffrag o[4][4];
  float lrun[4] = {0.f, 0.f, 0.f, 0.f};
#pragma unroll
  for (int nq = 0; nq < 4; ++nq)
#pragma unroll
    for (int dt = 0; dt < 4; ++dt) o[nq][dt] = (ffrag){0.f, 0.f, 0.f, 0.f};

  // staging: K [64t][64d], V [64d][64t], both 128B rows. Per instr: 8 rows
  // x 8 units of 16B; global unit = u ^ (row&7) (inverse of read swizzle).
  int srow = lane >> 3;
  int sug = (lane & 7) ^ srow;

  auto stage = [&](int buf, int t0) {
    char* Kd = (char*)&Klds[buf][0] + w * 2048;
    char* Vd = (char*)&Vlds[buf][0] + w * 2048;
    gload_lds16(Kseg + (size_t)(t0 + w * 16 + srow) * 512 + sug * 8, Kd);
    gload_lds16(Kseg + (size_t)(t0 + w * 16 + 8 + srow) * 512 + sug * 8,
                Kd + 1024);
    gload_lds16(Vseg + (size_t)(w * 16 + srow) * 512 + t0 + sug * 8, Vd);
    gload_lds16(Vseg + (size_t)(w * 16 + 8 + srow) * 512 + t0 + sug * 8,
                Vd + 1024);
  };

  auto body = [&](int buf) {
    const char* Kb = (const char*)&Klds[buf][0];
    const char* Vb = (const char*)&Vlds[buf][0];
#pragma unroll
    for (int s = 0; s < 2; ++s) {
      bfrag kk[2][2], vv[4];
#pragma unroll
      for (int mt = 0; mt < 2; ++mt)
#pragma unroll
        for (int ks = 0; ks < 2; ++ks) {
          int row = s * 32 + mt * 16 + ml;
          int byte = row * 128 + ks * 64 + quad * 16;
          kk[mt][ks] = *(const bfrag*)(Kb + (byte ^ ((row & 7) << 4)));
        }
#pragma unroll
      for (int dt = 0; dt < 4; ++dt) {
        int row = dt * 16 + ml;
        int byte = row * 128 + s * 64 + quad * 16;
        vv[dt] = *(const bfrag*)(Vb + (byte ^ ((row & 7) << 4)));
      }
#pragma unroll
      for (int nq = 0; nq < 4; ++nq) {
        ffrag c0 = {0.f, 0.f, 0.f, 0.f}, c1 = {0.f, 0.f, 0.f, 0.f};
        c0 = __builtin_amdgcn_mfma_f32_16x16x32_bf16(kk[0][0], qa[nq][0], c0, 0, 0, 0);
        c0 = __builtin_amdgcn_mfma_f32_16x16x32_bf16(kk[0][1], qa[nq][1], c0, 0, 0, 0);
        c1 = __builtin_amdgcn_mfma_f32_16x16x32_bf16(kk[1][0], qa[nq][0], c1, 0, 0, 0);
        c1 = __builtin_amdgcn_mfma_f32_16x16x32_bf16(kk[1][1], qa[nq][1], c1, 0, 0, 0);
        // P^T = 2^(S^T); lane (ml,qs) holds q=ml, t = s*32 + 4*qs+g (c0),
        // 16+4*qs+g (c1)
        float e0 = fexp2(c0[0]), e1 = fexp2(c0[1]);
        float e2 = fexp2(c0[2]), e3 = fexp2(c0[3]);
        float e4 = fexp2(c1[0]), e5 = fexp2(c1[1]);
        float e6 = fexp2(c1[2]), e7 = fexp2(c1[3]);
        lrun[nq] += ((e0 + e1) + (e2 + e3)) + ((e4 + e5) + (e6 + e7));
        // pack: A0=P0(t 4qs+0,1) A1=P1(4qs+2,3) A2=P2(16+4qs+0,1) A3=P3
        unsigned A0 = cvtpk(e0, e1), A1 = cvtpk(e2, e3);
        unsigned A2 = cvtpk(e4, e5), A3 = cvtpk(e6, e7);
        // C->B transpose, pure VALU: after swap32 (A0[32+i]<->A2[i]) and
        // swap16 (A0[16+i per 32]<->A2[i per 32]):
        //   A0 = [P0qs0, P0qs2, P2qs0, P2qs2] = pu[0] for quads 0..3
        //   A2 = [P0qs1, P0qs3, P2qs1, P2qs3] = pu[2]
        // (element-wise == old bpermute network r0..r7 + hi cndmask)
        asm("v_permlane32_swap_b32 %0, %1" : "+v"(A0), "+v"(A2));
        asm("v_permlane16_swap_b32 %0, %1" : "+v"(A0), "+v"(A2));
        asm("v_permlane32_swap_b32 %0, %1" : "+v"(A1), "+v"(A3));
        asm("v_permlane16_swap_b32 %0, %1" : "+v"(A1), "+v"(A3));
        uvec4 pu;
        pu[0] = A0;
        pu[1] = A1;
        pu[2] = A2;
        pu[3] = A3;
        bfrag pa = __builtin_bit_cast(bfrag, pu);
        // O^T[d][q] += V^T · P^T  (V t-cols of subtile s)
#pragma unroll
        for (int dt = 0; dt < 4; ++dt)
          o[nq][dt] = __builtin_amdgcn_mfma_f32_16x16x32_bf16(vv[dt], pa,
                                                              o[nq][dt], 0, 0, 0);
      }
    }
  };

  stage(0, 0);
  __syncthreads();
  int cur = 0;
#pragma unroll 1
  for (int jj = 0; jj < 7; ++jj) {
    stage(cur ^ 1, (jj + 1) * 64);  // prefetch next 64-t tile (async DMA)
    body(cur);                      // ds_read frags + MFMA on current
    __syncthreads();                // drains vmcnt -> next buffer ready
    cur ^= 1;
  }
  body(cur);

  // epilogue: reduce l across quads (2 shuffles), normalize, perm-scatter
#pragma unroll
  for (int nq = 0; nq < 4; ++nq) {
    float l = lrun[nq];
    l += __shfl_xor(l, 16);
    l += __shfl_xor(l, 32);
    float inv = 1.f / l;
    int sout = q0 + nq * 16 + ml;
    int om = perm[n * 512 + sout];
    size_t base = ((size_t)(b * 8192 + om)) * 512 + h * 64;
#pragma unroll
    for (int dt = 0; dt < 4; ++dt) {
      svec4 pk;
#pragma unroll
      for (int g = 0; g < 4; ++g) pk[g] = f2bf(o[nq][dt][g] * inv);
      *(svec4*)(aout + base + dt * 16 + quad * 4) = pk;
    }
  }
}

// ---------------- Kernel 4: output projection (16384x512 @ 512x512^T) ------
// v3: m97-structure LDS GEMM: 128x128 tile, BK=64, global_load_lds(16B)
// into linear LDS dbuf, 4 waves 2x2, acc 4x4/wave. Grid 512: rb=idx&127,
// cb=idx>>7 -> same-rb blocks land on same XCD.
__global__ __launch_bounds__(256, 2) void proj_kernel(
    const short* __restrict__ aout, const short* __restrict__ woutb,
    float* __restrict__ out) {
  __shared__ short As[2][128 * 64];
  __shared__ short Bs[2][128 * 64];
  int tid = threadIdx.x;
  int w = tid >> 6, lane = tid & 63;
  int ml = lane & 15, quad = lane >> 4;
  int rb = blockIdx.x & 127;
  int cb = blockIdx.x >> 7;
  int r0 = rb * 128, c0 = cb * 128;
  int wr = (w >> 1) * 64, wc = (w & 1) * 64;

  ffrag acc[4][4];
#pragma unroll
  for (int m = 0; m < 4; ++m)
#pragma unroll
    for (int n = 0; n < 4; ++n) acc[m][n] = (ffrag){0.f, 0.f, 0.f, 0.f};

  int srow = w * 32 + (lane >> 3);  // tile row this lane fetches
  int scol = (lane & 7) * 8;        // tile col (shorts)
  const short* gA = aout + (size_t)(r0 + srow) * 512 + scol;
  const short* gB = woutb + (size_t)(c0 + srow) * 512 + scol;

  auto stage = [&](int buf, int k0) {
#pragma unroll
    for (int i = 0; i < 4; ++i) {
      gload_lds16(gA + (size_t)i * 8 * 512 + k0,
                  (char*)&As[buf][0] + w * 4096 + i * 1024);
      gload_lds16(gB + (size_t)i * 8 * 512 + k0,
                  (char*)&Bs[buf][0] + w * 4096 + i * 1024);
    }
  };
  auto compute = [&](int buf) {
#pragma unroll
    for (int kk = 0; kk < 2; ++kk) {
      bfrag af[4], bf[4];
#pragma unroll
      for (int m = 0; m < 4; ++m)
        af[m] = *(const bfrag*)&As[buf][(wr + m * 16 + ml) * 64 + kk * 32 +
                                        quad * 8];
#pragma unroll
      for (int n = 0; n < 4; ++n)
        bf[n] = *(const bfrag*)&Bs[buf][(wc + n * 16 + ml) * 64 + kk * 32 +
                                        quad * 8];
#pragma unroll
      for (int m = 0; m < 4; ++m)
#pragma unroll
        for (int n = 0; n < 4; ++n)
          acc[m][n] = __builtin_amdgcn_mfma_f32_16x16x32_bf16(bf[n], af[m],
                                                              acc[m][n], 0, 0, 0);
    }
  };

  stage(0, 0);
  __syncthreads();
  int cur = 0;
#pragma unroll 1
  for (int t = 0; t < 7; ++t) {
    stage(cur ^ 1, (t + 1) * 64);  // prefetch next K-tile (async, in flight)
    compute(cur);                  // ds_read + MFMA on current
    __syncthreads();               // drains vmcnt -> next buffer ready
    cur ^= 1;
  }
  compute(cur);

#pragma unroll
  for (int m = 0; m < 4; ++m)
#pragma unroll
    for (int n = 0; n < 4; ++n)
      *(ffrag*)(out + (size_t)(r0 + wr + m * 16 + ml) * 512 + c0 + wc +
                n * 16 + quad * 4) = acc[m][n];
}

extern "C" void kernel_launch(void* const* d_in, const int* in_sizes, int n_in,
                              void* d_out, int out_size, void* d_ws,
                              size_t ws_size, hipStream_t stream) {
  const float* q = (const float*)d_in[0];
  const float* w_qkv = (const float*)d_in[3];
  const float* w_out = (const float*)d_in[4];
  float* out = (float*)d_out;

  char* ws = (char*)d_ws;
  int* perm = (int*)ws;                       //     32768 B
  short* xmean = (short*)(ws + 32768);        //   2097152 B
  short* weff = (short*)(ws + 2129920);       //    196608 B
  short* woutb = (short*)(ws + 2326528);      //    524288 B
  short* Qs = (short*)(ws + 2850816);         //  16777216 B
  short* Ks = (short*)(ws + 19628032);        //  16777216 B
  short* Vt = (short*)(ws + 36405248);        //  16777216 B
  short* aout = (short*)(ws + 53182464);      //  16777216 B  (total ~70 MB)

  prep_kernel<<<5536, 256, 0, stream>>>(q, w_qkv, w_out, xmean, weff, woutb,
                                        perm);
  qkv_kernel<<<1024, 256, 0, stream>>>(xmean, weff, perm, Qs, Ks, Vt);
  attn_kernel<<<512, 256, 0, stream>>>(Qs, Ks, Vt, perm, aout);
  proj_kernel<<<512, 256, 0, stream>>>(aout, woutb, out);
}

// Round 10
// 183.266 us; speedup vs baseline: 1.0029x; 1.0029x over previous
//
#include <hip/hip_runtime.h>

// B=2, M=8192, H=8, D=64, hd=512, S=512, n_seg=16
// d_in: q(8388608 f32), k, v (unused), w_qkv(786432 f32), w_out(262144 f32)
// d_out: 8388608 f32

typedef short bfrag __attribute__((ext_vector_type(8)));   // 8 bf16 (4 VGPR)
typedef float ffrag __attribute__((ext_vector_type(4)));   // MFMA C/D
typedef short svec4 __attribute__((ext_vector_type(4)));
typedef unsigned uvec4 __attribute__((ext_vector_type(4)));

__device__ inline short f2bf(float x) {  // RNE
  unsigned u = __builtin_bit_cast(unsigned, x);
  u = (u + 0x7fffu + ((u >> 16) & 1u)) >> 16;
  return (short)u;
}
__device__ inline float fexp2(float x) {
#if __has_builtin(__builtin_amdgcn_exp2f)
  return __builtin_amdgcn_exp2f(x);   // v_exp_f32 (hw is base-2)
#else
  return __expf(x * 0.6931471805599453f);
#endif
}
__device__ inline unsigned cvtpk(float a, float b) {  // lo=bf16(a), hi=bf16(b)
  unsigned r;
  asm("v_cvt_pk_bf16_f32 %0, %1, %2" : "=v"(r) : "v"(a), "v"(b));
  return r;
}
__device__ inline void gload_lds16(const void* g, void* l) {
  __builtin_amdgcn_global_load_lds(
      (const __attribute__((address_space(1))) unsigned*)g,
      (__attribute__((address_space(3))) unsigned*)l, 16, 0, 0);
}

// Hilbert d->(x,y) on 128x128 (Wikipedia pair; reference forward is the
// s-flip variant which is bit-identical for d, see round-2 analysis).
__device__ inline int d2xy128(int d) {
  int x = 0, y = 0, t = d;
  for (int s = 1; s < 128; s <<= 1) {
    int rx = 1 & (t >> 1);
    int ry = 1 & (t ^ rx);
    if (ry == 0) {
      if (rx == 1) { x = s - 1 - x; y = s - 1 - y; }
      int tt = x; x = y; y = tt;
    }
    x += s * rx;
    y += s * ry;
    t >>= 2;
  }
  return y * 128 + x;
}

// ---------------- Kernel 1: head-mean + eff. weights + perm (closed form) ---
__global__ __launch_bounds__(256) void prep_kernel(
    const float* __restrict__ q, const float* __restrict__ w_qkv,
    const float* __restrict__ w_out, short* __restrict__ xmean,
    short* __restrict__ weff, short* __restrict__ woutb,
    int* __restrict__ perm) {
  int i = blockIdx.x * 256 + threadIdx.x;
  if (i < 1048576) {
    int bm = i >> 6, d = i & 63;
    const float* p = q + (size_t)bm * 512 + d;
    float s = 0.f;
#pragma unroll
    for (int h = 0; h < 8; ++h) s += p[h * 64];
    xmean[i] = f2bf(s * 0.125f);
  } else if (i < 1048576 + 98304) {
    int j = i - 1048576;
    int f = j >> 6;
    const float* p = w_qkv + (size_t)f * 512 + (j & 63);
    float s = 0.f;
#pragma unroll
    for (int r = 0; r < 8; ++r) s += p[r * 64];
    if (f < 512) s *= 0.125f * 1.44269504088896f;  // D^-0.5 * log2(e)
    weff[j] = f2bf(s);
  } else if (i < 1048576 + 98304 + 262144) {
    int j = i - 1048576 - 98304;
    woutb[j] = f2bf(w_out[j]);
  } else if (i < 1048576 + 98304 + 262144 + 8192) {
    int r = i - (1048576 + 98304 + 262144);
    perm[r] = d2xy128(r < 4096 ? r : r + 8192);
  }
}

// ---------------- Kernel 2: QKV projection into permuted/segment layouts ----
// v2: W-quarter (384x64 = 48KB) staged to LDS once per block via
// global_load_lds(16B) with unit XOR-swizzle (u^=row&7); Q/K results bounce
// through a per-wave padded [16][72] LDS tile and store 16B/lane.
// Qs[b][p][f'], Ks[b][p][f'] (rows = permuted positions); Vt[b][n][h][d][t]
__global__ __launch_bounds__(256, 2) void qkv_kernel(
    const short* __restrict__ xmean, const short* __restrict__ weff,
    const int* __restrict__ perm, short* __restrict__ Qs,
    short* __restrict__ Ks, short* __restrict__ Vt) {
  __shared__ short Wlds[384 * 64];       // 48 KB, unit-swizzled rows of 128B
  __shared__ short Sb[4][2][16 * 72];    // per-wave dbuf bounce, 18 KB
  int tid = threadIdx.x;
  int w = tid >> 6, lane = tid & 63;
  int ml = lane & 15, quad = lane >> 4;
  int rg = blockIdx.x >> 2, fq = blockIdx.x & 3;
  int r0 = rg * 64 + w * 16;  // 16 permuted rows per wave
  int r = r0 + ml;
  int b = r >> 13, p = r & 8191;
  int src = (b << 13) + perm[p];
  bfrag a0 = *(const bfrag*)(xmean + (size_t)src * 64 + quad * 8);
  bfrag a1 = *(const bfrag*)(xmean + (size_t)src * 64 + 32 + quad * 8);
  int p0 = r0 & 8191;
  int bq = r0 >> 13;
  int nseg = p0 >> 9;
  int sbase = (p0 & 511) + quad * 4;

  // stage W quarter: wave w rows [w*96, w*96+96), 12 x 1KB instrs.
  {
    int lrow = lane >> 3;  // 0..7 within the 8-row chunk
    int lu = lane & 7;
    const short* wsrc = weff + (size_t)(fq * 384 + w * 96 + lrow) * 64 +
                        ((lu ^ (lrow & 7)) * 8);
#pragma unroll
    for (int i = 0; i < 12; ++i)
      gload_lds16(wsrc + (size_t)i * 8 * 64,
                  (char*)Wlds + w * 12288 + i * 1024);
  }
  __syncthreads();

#pragma unroll 1
  for (int gg = 0; gg < 6; ++gg) {
    int nt0 = fq * 24 + gg * 4;
    int f0g = nt0 * 16;
    short* sb = &Sb[w][gg & 1][0];
    if (f0g < 1024) {
      // Q/K group: 4 tiles -> bounce -> 2 coalesced 16B/lane stores
#pragma unroll
      for (int t = 0; t < 4; ++t) {
        int row = (gg * 4 + t) * 16 + ml;  // local W row
        const char* Wb = (const char*)Wlds + row * 128;
        int sw = (row & 7) << 4;
        bfrag wf0 = *(const bfrag*)(Wb + ((quad << 4) ^ sw));
        bfrag wf1 = *(const bfrag*)(Wb + (((4 + quad) << 4) ^ sw));
        ffrag acc = {0.f, 0.f, 0.f, 0.f};
        // D[f][row]: lane ml = row(pos), quad*4+g = f
        acc = __builtin_amdgcn_mfma_f32_16x16x32_bf16(wf0, a0, acc, 0, 0, 0);
        acc = __builtin_amdgcn_mfma_f32_16x16x32_bf16(wf1, a1, acc, 0, 0, 0);
        svec4 pk;
#pragma unroll
        for (int g = 0; g < 4; ++g) pk[g] = f2bf(acc[g]);
        *(svec4*)((char*)sb + ml * 144 + t * 32 + quad * 8) = pk;
      }
      __builtin_amdgcn_sched_barrier(0);  // keep reads after writes
      int rrow = lane >> 3;
      int cu = lane & 7;
      bfrag v0 = *(const bfrag*)((char*)sb + rrow * 144 + cu * 16);
      bfrag v1 = *(const bfrag*)((char*)sb + (rrow + 8) * 144 + cu * 16);
      short* dst = (f0g < 512) ? Qs : Ks;
      int fo = f0g & 511;
      *(bfrag*)(dst + (size_t)(r0 + rrow) * 512 + fo + cu * 8) = v0;
      *(bfrag*)(dst + (size_t)(r0 + rrow + 8) * 512 + fo + cu * 8) = v1;
    } else {
      // V group: D[row][f] orientation, direct svec4 stores into Vt
#pragma unroll
      for (int t = 0; t < 4; ++t) {
        int nt = nt0 + t;
        int row = (gg * 4 + t) * 16 + ml;
        const char* Wb = (const char*)Wlds + row * 128;
        int sw = (row & 7) << 4;
        bfrag wf0 = *(const bfrag*)(Wb + ((quad << 4) ^ sw));
        bfrag wf1 = *(const bfrag*)(Wb + (((4 + quad) << 4) ^ sw));
        ffrag acc = {0.f, 0.f, 0.f, 0.f};
        acc = __builtin_amdgcn_mfma_f32_16x16x32_bf16(a0, wf0, acc, 0, 0, 0);
        acc = __builtin_amdgcn_mfma_f32_16x16x32_bf16(a1, wf1, acc, 0, 0, 0);
        int fl = nt * 16 + ml - 1024;
        int hh = fl >> 6, dd = fl & 63;
        svec4 pk;
#pragma unroll
        for (int g = 0; g < 4; ++g) pk[g] = f2bf(acc[g]);
        *(svec4*)(Vt + ((((size_t)bq * 16 + nseg) * 8 + hh) * 64 + dd) * 512 +
                  sbase) = pk;
      }
    }
  }
}

// ---------------- Kernel 3: segment attention, no-max softmax, S^T=K·Q^T ----
// v7: counted-vmcnt pipeline (T3/T4). v5/v6 post-mortems: attn pinned ~33us
// across 2x occupancy (R7) and 2x DS-volume (R9) changes; only chain-latency
// removal (permlane, R8) moved it -> the stall is __syncthreads' implicit
// s_waitcnt vmcnt(0) draining the global_load_lds queue every tile (m233:
// ~70% of 2-phase time; m218: counted vs drain0 = +38-73%). Now: 2 tiles in
// flight; per iter wait vmcnt(4) (own tile's 4 loads; next tile's stay in
// flight across the barrier), raw s_barrier (no drain), body, raw barrier,
// restage j+2 into the just-read buffer. vmcnt accounting: 4 loads/tile/wave;
// early qa global loads only make the wait conservative. Structure else =
// v6: nq=4, KVBLK=64, permlane transpose, 512 blocks.
__global__ __launch_bounds__(256, 2) void attn_kernel(
    const short* __restrict__ Qs, const short* __restrict__ Ks,
    const short* __restrict__ Vt, const int* __restrict__ perm,
    short* __restrict__ aout) {
  __shared__ short Klds[2][64 * 64];
  __shared__ short Vlds[2][64 * 64];
  int tid = threadIdx.x;
  int w = tid >> 6, lane = tid & 63;
  int ml = lane & 15, quad = lane >> 4;
  int sh = blockIdx.x & 255;
  int qq = blockIdx.x >> 8;  // 0..1
  int b = sh >> 7;
  int n = (sh >> 3) & 15;
  int h = sh & 7;
  size_t segrow = (size_t)(b * 8192 + n * 512);
  const short* Qseg = Qs + segrow * 512 + h * 64;
  const short* Kseg = Ks + segrow * 512 + h * 64;
  const short* Vseg = Vt + (((size_t)(b * 16 + n) * 8 + h) * 64) * 512;
  int q0 = qq * 256 + w * 64;  // 64 q-cols per wave (4 chains)
  bfrag qa[4][2];
#pragma unroll
  for (int nq = 0; nq < 4; ++nq)
#pragma unroll
    for (int ks = 0; ks < 2; ++ks)
      qa[nq][ks] = *(const bfrag*)(Qseg + (size_t)(q0 + nq * 16 + ml) * 512 +
                                   ks * 32 + quad * 8);
  ffrag o[4][4];
  float lrun[4] = {0.f, 0.f, 0.f, 0.f};
#pragma unroll
  for (int nq = 0; nq < 4; ++nq)
#pragma unroll
    for (int dt = 0; dt < 4; ++dt) o[nq][dt] = (ffrag){0.f, 0.f, 0.f, 0.f};

  // staging: K [64t][64d], V [64d][64t], both 128B rows. Per instr: 8 rows
  // x 8 units of 16B; global unit = u ^ (row&7) (inverse of read swizzle).
  int srow = lane >> 3;
  int sug = (lane & 7) ^ srow;

  auto stage = [&](int buf, int t0) {
    char* Kd = (char*)&Klds[buf][0] + w * 2048;
    char* Vd = (char*)&Vlds[buf][0] + w * 2048;
    gload_lds16(Kseg + (size_t)(t0 + w * 16 + srow) * 512 + sug * 8, Kd);
    gload_lds16(Kseg + (size_t)(t0 + w * 16 + 8 + srow) * 512 + sug * 8,
                Kd + 1024);
    gload_lds16(Vseg + (size_t)(w * 16 + srow) * 512 + t0 + sug * 8, Vd);
    gload_lds16(Vseg + (size_t)(w * 16 + 8 + srow) * 512 + t0 + sug * 8,
                Vd + 1024);
  };

  auto body = [&](int buf) {
    const char* Kb = (const char*)&Klds[buf][0];
    const char* Vb = (const char*)&Vlds[buf][0];
#pragma unroll
    for (int s = 0; s < 2; ++s) {
      bfrag kk[2][2], vv[4];
#pragma unroll
      for (int mt = 0; mt < 2; ++mt)
#pragma unroll
        for (int ks = 0; ks < 2; ++ks) {
          int row = s * 32 + mt * 16 + ml;
          int byte = row * 128 + ks * 64 + quad * 16;
          kk[mt][ks] = *(const bfrag*)(Kb + (byte ^ ((row & 7) << 4)));
        }
#pragma unroll
      for (int dt = 0; dt < 4; ++dt) {
        int row = dt * 16 + ml;
        int byte = row * 128 + s * 64 + quad * 16;
        vv[dt] = *(const bfrag*)(Vb + (byte ^ ((row & 7) << 4)));
      }
#pragma unroll
      for (int nq = 0; nq < 4; ++nq) {
        ffrag c0 = {0.f, 0.f, 0.f, 0.f}, c1 = {0.f, 0.f, 0.f, 0.f};
        c0 = __builtin_amdgcn_mfma_f32_16x16x32_bf16(kk[0][0], qa[nq][0], c0, 0, 0, 0);
        c0 = __builtin_amdgcn_mfma_f32_16x16x32_bf16(kk[0][1], qa[nq][1], c0, 0, 0, 0);
        c1 = __builtin_amdgcn_mfma_f32_16x16x32_bf16(kk[1][0], qa[nq][0], c1, 0, 0, 0);
        c1 = __builtin_amdgcn_mfma_f32_16x16x32_bf16(kk[1][1], qa[nq][1], c1, 0, 0, 0);
        // P^T = 2^(S^T); lane (ml,qs) holds q=ml, t = s*32 + 4*qs+g (c0),
        // 16+4*qs+g (c1)
        float e0 = fexp2(c0[0]), e1 = fexp2(c0[1]);
        float e2 = fexp2(c0[2]), e3 = fexp2(c0[3]);
        float e4 = fexp2(c1[0]), e5 = fexp2(c1[1]);
        float e6 = fexp2(c1[2]), e7 = fexp2(c1[3]);
        lrun[nq] += ((e0 + e1) + (e2 + e3)) + ((e4 + e5) + (e6 + e7));
        // pack: A0=P0(t 4qs+0,1) A1=P1(4qs+2,3) A2=P2(16+4qs+0,1) A3=P3
        unsigned A0 = cvtpk(e0, e1), A1 = cvtpk(e2, e3);
        unsigned A2 = cvtpk(e4, e5), A3 = cvtpk(e6, e7);
        // C->B transpose, pure VALU (== old bpermute network, verified):
        asm("v_permlane32_swap_b32 %0, %1" : "+v"(A0), "+v"(A2));
        asm("v_permlane16_swap_b32 %0, %1" : "+v"(A0), "+v"(A2));
        asm("v_permlane32_swap_b32 %0, %1" : "+v"(A1), "+v"(A3));
        asm("v_permlane16_swap_b32 %0, %1" : "+v"(A1), "+v"(A3));
        uvec4 pu;
        pu[0] = A0;
        pu[1] = A1;
        pu[2] = A2;
        pu[3] = A3;
        bfrag pa = __builtin_bit_cast(bfrag, pu);
        // O^T[d][q] += V^T · P^T  (V t-cols of subtile s)
#pragma unroll
        for (int dt = 0; dt < 4; ++dt)
          o[nq][dt] = __builtin_amdgcn_mfma_f32_16x16x32_bf16(vv[dt], pa,
                                                              o[nq][dt], 0, 0, 0);
      }
    }
  };

  // counted-vmcnt pipeline, 2 tiles deep (8 tiles total, t = jj*64)
  stage(0, 0);
  stage(1, 64);
#pragma unroll 1
  for (int jj = 0; jj < 7; ++jj) {
    asm volatile("s_waitcnt vmcnt(4)" ::: "memory");  // tile jj landed
    __builtin_amdgcn_s_barrier();                     // all waves' quarters in
    body(jj & 1);
    if (jj < 6) {
      __builtin_amdgcn_s_barrier();                   // readers done with buf
      stage(jj & 1, (jj + 2) * 64);                   // restage 2 ahead
    }
  }
  asm volatile("s_waitcnt vmcnt(0)" ::: "memory");
  __builtin_amdgcn_s_barrier();
  body(1);

  // epilogue: reduce l across quads (2 shuffles), normalize, perm-scatter
#pragma unroll
  for (int nq = 0; nq < 4; ++nq) {
    float l = lrun[nq];
    l += __shfl_xor(l, 16);
    l += __shfl_xor(l, 32);
    float inv = 1.f / l;
    int sout = q0 + nq * 16 + ml;
    int om = perm[n * 512 + sout];
    size_t base = ((size_t)(b * 8192 + om)) * 512 + h * 64;
#pragma unroll
    for (int dt = 0; dt < 4; ++dt) {
      svec4 pk;
#pragma unroll
      for (int g = 0; g < 4; ++g) pk[g] = f2bf(o[nq][dt][g] * inv);
      *(svec4*)(aout + base + dt * 16 + quad * 4) = pk;
    }
  }
}

// ---------------- Kernel 4: output projection (16384x512 @ 512x512^T) ------
// v4: counted-vmcnt pipeline (same T3/T4 rationale as attn v7; 8 loads/tile
// per wave -> wait vmcnt(8)). Structure else = v3: 128x128 tile, BK=64,
// global_load_lds(16B) linear LDS dbuf, 4 waves 2x2, acc 4x4/wave.
__global__ __launch_bounds__(256, 2) void proj_kernel(
    const short* __restrict__ aout, const short* __restrict__ woutb,
    float* __restrict__ out) {
  __shared__ short As[2][128 * 64];
  __shared__ short Bs[2][128 * 64];
  int tid = threadIdx.x;
  int w = tid >> 6, lane = tid & 63;
  int ml = lane & 15, quad = lane >> 4;
  int rb = blockIdx.x & 127;
  int cb = blockIdx.x >> 7;
  int r0 = rb * 128, c0 = cb * 128;
  int wr = (w >> 1) * 64, wc = (w & 1) * 64;

  ffrag acc[4][4];
#pragma unroll
  for (int m = 0; m < 4; ++m)
#pragma unroll
    for (int n = 0; n < 4; ++n) acc[m][n] = (ffrag){0.f, 0.f, 0.f, 0.f};

  int srow = w * 32 + (lane >> 3);  // tile row this lane fetches
  int scol = (lane & 7) * 8;        // tile col (shorts)
  const short* gA = aout + (size_t)(r0 + srow) * 512 + scol;
  const short* gB = woutb + (size_t)(c0 + srow) * 512 + scol;

  auto stage = [&](int buf, int k0) {
#pragma unroll
    for (int i = 0; i < 4; ++i) {
      gload_lds16(gA + (size_t)i * 8 * 512 + k0,
                  (char*)&As[buf][0] + w * 4096 + i * 1024);
      gload_lds16(gB + (size_t)i * 8 * 512 + k0,
                  (char*)&Bs[buf][0] + w * 4096 + i * 1024);
    }
  };
  auto compute = [&](int buf) {
#pragma unroll
    for (int kk = 0; kk < 2; ++kk) {
      bfrag af[4], bf[4];
#pragma unroll
      for (int m = 0; m < 4; ++m)
        af[m] = *(const bfrag*)&As[buf][(wr + m * 16 + ml) * 64 + kk * 32 +
                                        quad * 8];
#pragma unroll
      for (int n = 0; n < 4; ++n)
        bf[n] = *(const bfrag*)&Bs[buf][(wc + n * 16 + ml) * 64 + kk * 32 +
                                        quad * 8];
#pragma unroll
      for (int m = 0; m < 4; ++m)
#pragma unroll
        for (int n = 0; n < 4; ++n)
          acc[m][n] = __builtin_amdgcn_mfma_f32_16x16x32_bf16(bf[n], af[m],
                                                              acc[m][n], 0, 0, 0);
    }
  };

  // counted-vmcnt pipeline, 2 tiles deep (8 k-tiles, k = t*64)
  stage(0, 0);
  stage(1, 64);
#pragma unroll 1
  for (int t = 0; t < 7; ++t) {
    asm volatile("s_waitcnt vmcnt(8)" ::: "memory");  // tile t landed
    __builtin_amdgcn_s_barrier();
    compute(t & 1);
    if (t < 6) {
      __builtin_amdgcn_s_barrier();
      stage(t & 1, (t + 2) * 64);
    }
  }
  asm volatile("s_waitcnt vmcnt(0)" ::: "memory");
  __builtin_amdgcn_s_barrier();
  compute(1);

#pragma unroll
  for (int m = 0; m < 4; ++m)
#pragma unroll
    for (int n = 0; n < 4; ++n)
      *(ffrag*)(out + (size_t)(r0 + wr + m * 16 + ml) * 512 + c0 + wc +
                n * 16 + quad * 4) = acc[m][n];
}

extern "C" void kernel_launch(void* const* d_in, const int* in_sizes, int n_in,
                              void* d_out, int out_size, void* d_ws,
                              size_t ws_size, hipStream_t stream) {
  const float* q = (const float*)d_in[0];
  const float* w_qkv = (const float*)d_in[3];
  const float* w_out = (const float*)d_in[4];
  float* out = (float*)d_out;

  char* ws = (char*)d_ws;
  int* perm = (int*)ws;                       //     32768 B
  short* xmean = (short*)(ws + 32768);        //   2097152 B
  short* weff = (short*)(ws + 2129920);       //    196608 B
  short* woutb = (short*)(ws + 2326528);      //    524288 B
  short* Qs = (short*)(ws + 2850816);         //  16777216 B
  short* Ks = (short*)(ws + 19628032);        //  16777216 B
  short* Vt = (short*)(ws + 36405248);        //  16777216 B
  short* aout = (short*)(ws + 53182464);      //  16777216 B  (total ~70 MB)

  prep_kernel<<<5536, 256, 0, stream>>>(q, w_qkv, w_out, xmean, weff, woutb,
                                        perm);
  qkv_kernel<<<1024, 256, 0, stream>>>(xmean, weff, perm, Qs, Ks, Vt);
  attn_kernel<<<512, 256, 0, stream>>>(Qs, Ks, Vt, perm, aout);
  proj_kernel<<<512, 256, 0, stream>>>(aout, woutb, out);
}

// Round 11
// 181.314 us; speedup vs baseline: 1.0137x; 1.0108x over previous
//
#include <hip/hip_runtime.h>

// B=2, M=8192, H=8, D=64, hd=512, S=512, n_seg=16
// d_in: q(8388608 f32), k, v (unused), w_qkv(786432 f32), w_out(262144 f32)
// d_out: 8388608 f32

typedef short bfrag __attribute__((ext_vector_type(8)));   // 8 bf16 (4 VGPR)
typedef float ffrag __attribute__((ext_vector_type(4)));   // MFMA C/D
typedef short svec4 __attribute__((ext_vector_type(4)));
typedef unsigned uvec4 __attribute__((ext_vector_type(4)));

__device__ inline short f2bf(float x) {  // RNE
  unsigned u = __builtin_bit_cast(unsigned, x);
  u = (u + 0x7fffu + ((u >> 16) & 1u)) >> 16;
  return (short)u;
}
__device__ inline float fexp2(float x) {
#if __has_builtin(__builtin_amdgcn_exp2f)
  return __builtin_amdgcn_exp2f(x);   // v_exp_f32 (hw is base-2)
#else
  return __expf(x * 0.6931471805599453f);
#endif
}
__device__ inline unsigned cvtpk(float a, float b) {  // lo=bf16(a), hi=bf16(b)
  unsigned r;
  asm("v_cvt_pk_bf16_f32 %0, %1, %2" : "=v"(r) : "v"(a), "v"(b));
  return r;
}
__device__ inline void gload_lds16(const void* g, void* l) {
  __builtin_amdgcn_global_load_lds(
      (const __attribute__((address_space(1))) unsigned*)g,
      (__attribute__((address_space(3))) unsigned*)l, 16, 0, 0);
}

// Hilbert d->(x,y) on 128x128 (Wikipedia pair; reference forward is the
// s-flip variant which is bit-identical for d, see round-2 analysis).
__device__ inline int d2xy128(int d) {
  int x = 0, y = 0, t = d;
  for (int s = 1; s < 128; s <<= 1) {
    int rx = 1 & (t >> 1);
    int ry = 1 & (t ^ rx);
    if (ry == 0) {
      if (rx == 1) { x = s - 1 - x; y = s - 1 - y; }
      int tt = x; x = y; y = tt;
    }
    x += s * rx;
    y += s * ry;
    t >>= 2;
  }
  return y * 128 + x;
}

// ---------------- Kernel 1: head-mean + eff. weights + perm/inv ------------
__global__ __launch_bounds__(256) void prep_kernel(
    const float* __restrict__ q, const float* __restrict__ w_qkv,
    const float* __restrict__ w_out, short* __restrict__ xmean,
    short* __restrict__ weff, short* __restrict__ woutb,
    int* __restrict__ perm, int* __restrict__ inv) {
  int i = blockIdx.x * 256 + threadIdx.x;
  if (i < 1048576) {
    int bm = i >> 6, d = i & 63;
    const float* p = q + (size_t)bm * 512 + d;
    float s = 0.f;
#pragma unroll
    for (int h = 0; h < 8; ++h) s += p[h * 64];
    xmean[i] = f2bf(s * 0.125f);
  } else if (i < 1048576 + 98304) {
    int j = i - 1048576;
    int f = j >> 6;
    const float* p = w_qkv + (size_t)f * 512 + (j & 63);
    float s = 0.f;
#pragma unroll
    for (int r = 0; r < 8; ++r) s += p[r * 64];
    if (f < 512) s *= 0.125f * 1.44269504088896f;  // D^-0.5 * log2(e)
    weff[j] = f2bf(s);
  } else if (i < 1048576 + 98304 + 262144) {
    int j = i - 1048576 - 98304;
    woutb[j] = f2bf(w_out[j]);
  } else if (i < 1048576 + 98304 + 262144 + 8192) {
    int r = i - (1048576 + 98304 + 262144);
    int v = d2xy128(r < 4096 ? r : r + 8192);
    perm[r] = v;
    inv[v] = r;  // bijective scatter: inv[perm[r]] = r
  }
}

// ---------------- Kernel 2: QKV projection into permuted/segment layouts ----
// v3: adds V-store bounce. v2 fixed Q/K store granule (16B/lane -> 128B
// chunks); V still wrote 8B/lane at 1KB stride = 4x sector amplification
// (~48MB wasted write BW). Now V's 4 tiles/gg (64 f x 16 pos) bounce
// through the same per-wave Sb buffer ([64][16] shorts, exact fit) and are
// re-read as (dd, pos-quartet): 4 lanes emit one contiguous 32B chunk per
// f-row -> amplification 1x. Values bit-identical.
__global__ __launch_bounds__(256, 2) void qkv_kernel(
    const short* __restrict__ xmean, const short* __restrict__ weff,
    const int* __restrict__ perm, short* __restrict__ Qs,
    short* __restrict__ Ks, short* __restrict__ Vt) {
  __shared__ short Wlds[384 * 64];       // 48 KB, unit-swizzled rows of 128B
  __shared__ short Sb[4][2][16 * 72];    // per-wave dbuf bounce, 18 KB
  int tid = threadIdx.x;
  int w = tid >> 6, lane = tid & 63;
  int ml = lane & 15, quad = lane >> 4;
  int rg = blockIdx.x >> 2, fq = blockIdx.x & 3;
  int r0 = rg * 64 + w * 16;  // 16 permuted rows per wave
  int r = r0 + ml;
  int b = r >> 13, p = r & 8191;
  int src = (b << 13) + perm[p];
  bfrag a0 = *(const bfrag*)(xmean + (size_t)src * 64 + quad * 8);
  bfrag a1 = *(const bfrag*)(xmean + (size_t)src * 64 + 32 + quad * 8);
  int p0 = r0 & 8191;
  int bq = r0 >> 13;
  int nseg = p0 >> 9;

  // stage W quarter: wave w rows [w*96, w*96+96), 12 x 1KB instrs.
  {
    int lrow = lane >> 3;  // 0..7 within the 8-row chunk
    int lu = lane & 7;
    const short* wsrc = weff + (size_t)(fq * 384 + w * 96 + lrow) * 64 +
                        ((lu ^ (lrow & 7)) * 8);
#pragma unroll
    for (int i = 0; i < 12; ++i)
      gload_lds16(wsrc + (size_t)i * 8 * 64,
                  (char*)Wlds + w * 12288 + i * 1024);
  }
  __syncthreads();

#pragma unroll 1
  for (int gg = 0; gg < 6; ++gg) {
    int nt0 = fq * 24 + gg * 4;
    int f0g = nt0 * 16;
    short* sb = &Sb[w][gg & 1][0];
    if (f0g < 1024) {
      // Q/K group: 4 tiles -> bounce -> 2 coalesced 16B/lane stores
#pragma unroll
      for (int t = 0; t < 4; ++t) {
        int row = (gg * 4 + t) * 16 + ml;  // local W row
        const char* Wb = (const char*)Wlds + row * 128;
        int sw = (row & 7) << 4;
        bfrag wf0 = *(const bfrag*)(Wb + ((quad << 4) ^ sw));
        bfrag wf1 = *(const bfrag*)(Wb + (((4 + quad) << 4) ^ sw));
        ffrag acc = {0.f, 0.f, 0.f, 0.f};
        // D[f][row]: lane ml = row(pos), quad*4+g = f
        acc = __builtin_amdgcn_mfma_f32_16x16x32_bf16(wf0, a0, acc, 0, 0, 0);
        acc = __builtin_amdgcn_mfma_f32_16x16x32_bf16(wf1, a1, acc, 0, 0, 0);
        svec4 pk;
#pragma unroll
        for (int g = 0; g < 4; ++g) pk[g] = f2bf(acc[g]);
        *(svec4*)((char*)sb + ml * 144 + t * 32 + quad * 8) = pk;
      }
      __builtin_amdgcn_sched_barrier(0);  // keep reads after writes
      int rrow = lane >> 3;
      int cu = lane & 7;
      bfrag v0 = *(const bfrag*)((char*)sb + rrow * 144 + cu * 16);
      bfrag v1 = *(const bfrag*)((char*)sb + (rrow + 8) * 144 + cu * 16);
      short* dst = (f0g < 512) ? Qs : Ks;
      int fo = f0g & 511;
      *(bfrag*)(dst + (size_t)(r0 + rrow) * 512 + fo + cu * 8) = v0;
      *(bfrag*)(dst + (size_t)(r0 + rrow + 8) * 512 + fo + cu * 8) = v1;
    } else {
      // V group: 4 tiles into [64 dd][16 pos] LDS bounce, then 32B stores
#pragma unroll
      for (int t = 0; t < 4; ++t) {
        int row = (gg * 4 + t) * 16 + ml;
        const char* Wb = (const char*)Wlds + row * 128;
        int sw = (row & 7) << 4;
        bfrag wf0 = *(const bfrag*)(Wb + ((quad << 4) ^ sw));
        bfrag wf1 = *(const bfrag*)(Wb + (((4 + quad) << 4) ^ sw));
        ffrag acc = {0.f, 0.f, 0.f, 0.f};
        acc = __builtin_amdgcn_mfma_f32_16x16x32_bf16(a0, wf0, acc, 0, 0, 0);
        acc = __builtin_amdgcn_mfma_f32_16x16x32_bf16(a1, wf1, acc, 0, 0, 0);
        // lane holds f = t*16+ml (within gg's 64), pos = quad*4+g
        svec4 pk;
#pragma unroll
        for (int g = 0; g < 4; ++g) pk[g] = f2bf(acc[g]);
        *(svec4*)((char*)sb + ((t * 16 + ml) * 16 + quad * 4) * 2) = pk;
      }
      __builtin_amdgcn_sched_barrier(0);  // reads after writes (intra-wave)
      int pos4 = (lane & 3) * 4;  // position quartet
      int ddl = lane >> 2;        // 0..15
#pragma unroll
      for (int rr = 0; rr < 4; ++rr) {
        int dd64 = rr * 16 + ddl;  // f index within gg's 64
        svec4 v = *(const svec4*)((char*)sb + (dd64 * 16 + pos4) * 2);
        int fl = f0g + dd64 - 1024;
        int hh = fl >> 6, dd = fl & 63;
        *(svec4*)(Vt + ((((size_t)bq * 16 + nseg) * 8 + hh) * 64 + dd) * 512 +
                  (p0 & 511) + pos4) = v;
      }
      __builtin_amdgcn_sched_barrier(0);  // next gg's writes after reads
    }
  }
}

// ---------------- Kernel 3: segment attention, no-max softmax, S^T=K·Q^T ----
// v8: segment-order epilogue. R7 counters: WRITE_SIZE 30.7MB for 16.4MB of
// data -> the perm-scatter (8B/lane to Hilbert-random rows) was ~1.9x write
// amplification + an in-chain perm[] gather. Now aout is stored in SEGMENT
// order (row = b*8192+n*512+sout; quads form full 32B sectors, sequential
// rows) and proj absorbs the permutation as a row-gather via inv[].
// Structure else = v7: nq=4, KVBLK=64, permlane transpose, counted-vmcnt
// 2-deep pipeline, 512 blocks.
__global__ __launch_bounds__(256, 2) void attn_kernel(
    const short* __restrict__ Qs, const short* __restrict__ Ks,
    const short* __restrict__ Vt, const int* __restrict__ perm,
    short* __restrict__ aout) {
  __shared__ short Klds[2][64 * 64];
  __shared__ short Vlds[2][64 * 64];
  int tid = threadIdx.x;
  int w = tid >> 6, lane = tid & 63;
  int ml = lane & 15, quad = lane >> 4;
  int sh = blockIdx.x & 255;
  int qq = blockIdx.x >> 8;  // 0..1
  int b = sh >> 7;
  int n = (sh >> 3) & 15;
  int h = sh & 7;
  size_t segrow = (size_t)(b * 8192 + n * 512);
  const short* Qseg = Qs + segrow * 512 + h * 64;
  const short* Kseg = Ks + segrow * 512 + h * 64;
  const short* Vseg = Vt + (((size_t)(b * 16 + n) * 8 + h) * 64) * 512;
  int q0 = qq * 256 + w * 64;  // 64 q-cols per wave (4 chains)
  bfrag qa[4][2];
#pragma unroll
  for (int nq = 0; nq < 4; ++nq)
#pragma unroll
    for (int ks = 0; ks < 2; ++ks)
      qa[nq][ks] = *(const bfrag*)(Qseg + (size_t)(q0 + nq * 16 + ml) * 512 +
                                   ks * 32 + quad * 8);
  ffrag o[4][4];
  float lrun[4] = {0.f, 0.f, 0.f, 0.f};
#pragma unroll
  for (int nq = 0; nq < 4; ++nq)
#pragma unroll
    for (int dt = 0; dt < 4; ++dt) o[nq][dt] = (ffrag){0.f, 0.f, 0.f, 0.f};

  // staging: K [64t][64d], V [64d][64t], both 128B rows. Per instr: 8 rows
  // x 8 units of 16B; global unit = u ^ (row&7) (inverse of read swizzle).
  int srow = lane >> 3;
  int sug = (lane & 7) ^ srow;

  auto stage = [&](int buf, int t0) {
    char* Kd = (char*)&Klds[buf][0] + w * 2048;
    char* Vd = (char*)&Vlds[buf][0] + w * 2048;
    gload_lds16(Kseg + (size_t)(t0 + w * 16 + srow) * 512 + sug * 8, Kd);
    gload_lds16(Kseg + (size_t)(t0 + w * 16 + 8 + srow) * 512 + sug * 8,
                Kd + 1024);
    gload_lds16(Vseg + (size_t)(w * 16 + srow) * 512 + t0 + sug * 8, Vd);
    gload_lds16(Vseg + (size_t)(w * 16 + 8 + srow) * 512 + t0 + sug * 8,
                Vd + 1024);
  };

  auto body = [&](int buf) {
    const char* Kb = (const char*)&Klds[buf][0];
    const char* Vb = (const char*)&Vlds[buf][0];
#pragma unroll
    for (int s = 0; s < 2; ++s) {
      bfrag kk[2][2], vv[4];
#pragma unroll
      for (int mt = 0; mt < 2; ++mt)
#pragma unroll
        for (int ks = 0; ks < 2; ++ks) {
          int row = s * 32 + mt * 16 + ml;
          int byte = row * 128 + ks * 64 + quad * 16;
          kk[mt][ks] = *(const bfrag*)(Kb + (byte ^ ((row & 7) << 4)));
        }
#pragma unroll
      for (int dt = 0; dt < 4; ++dt) {
        int row = dt * 16 + ml;
        int byte = row * 128 + s * 64 + quad * 16;
        vv[dt] = *(const bfrag*)(Vb + (byte ^ ((row & 7) << 4)));
      }
#pragma unroll
      for (int nq = 0; nq < 4; ++nq) {
        ffrag c0 = {0.f, 0.f, 0.f, 0.f}, c1 = {0.f, 0.f, 0.f, 0.f};
        c0 = __builtin_amdgcn_mfma_f32_16x16x32_bf16(kk[0][0], qa[nq][0], c0, 0, 0, 0);
        c0 = __builtin_amdgcn_mfma_f32_16x16x32_bf16(kk[0][1], qa[nq][1], c0, 0, 0, 0);
        c1 = __builtin_amdgcn_mfma_f32_16x16x32_bf16(kk[1][0], qa[nq][0], c1, 0, 0, 0);
        c1 = __builtin_amdgcn_mfma_f32_16x16x32_bf16(kk[1][1], qa[nq][1], c1, 0, 0, 0);
        // P^T = 2^(S^T); lane (ml,qs) holds q=ml, t = s*32 + 4*qs+g (c0),
        // 16+4*qs+g (c1)
        float e0 = fexp2(c0[0]), e1 = fexp2(c0[1]);
        float e2 = fexp2(c0[2]), e3 = fexp2(c0[3]);
        float e4 = fexp2(c1[0]), e5 = fexp2(c1[1]);
        float e6 = fexp2(c1[2]), e7 = fexp2(c1[3]);
        lrun[nq] += ((e0 + e1) + (e2 + e3)) + ((e4 + e5) + (e6 + e7));
        // pack: A0=P0(t 4qs+0,1) A1=P1(4qs+2,3) A2=P2(16+4qs+0,1) A3=P3
        unsigned A0 = cvtpk(e0, e1), A1 = cvtpk(e2, e3);
        unsigned A2 = cvtpk(e4, e5), A3 = cvtpk(e6, e7);
        // C->B transpose, pure VALU (== old bpermute network, verified):
        asm("v_permlane32_swap_b32 %0, %1" : "+v"(A0), "+v"(A2));
        asm("v_permlane16_swap_b32 %0, %1" : "+v"(A0), "+v"(A2));
        asm("v_permlane32_swap_b32 %0, %1" : "+v"(A1), "+v"(A3));
        asm("v_permlane16_swap_b32 %0, %1" : "+v"(A1), "+v"(A3));
        uvec4 pu;
        pu[0] = A0;
        pu[1] = A1;
        pu[2] = A2;
        pu[3] = A3;
        bfrag pa = __builtin_bit_cast(bfrag, pu);
        // O^T[d][q] += V^T · P^T  (V t-cols of subtile s)
#pragma unroll
        for (int dt = 0; dt < 4; ++dt)
          o[nq][dt] = __builtin_amdgcn_mfma_f32_16x16x32_bf16(vv[dt], pa,
                                                              o[nq][dt], 0, 0, 0);
      }
    }
  };

  // counted-vmcnt pipeline, 2 tiles deep (8 tiles total, t = jj*64)
  stage(0, 0);
  stage(1, 64);
#pragma unroll 1
  for (int jj = 0; jj < 7; ++jj) {
    asm volatile("s_waitcnt vmcnt(4)" ::: "memory");  // tile jj landed
    __builtin_amdgcn_s_barrier();                     // all waves' quarters in
    body(jj & 1);
    if (jj < 6) {
      __builtin_amdgcn_s_barrier();                   // readers done with buf
      stage(jj & 1, (jj + 2) * 64);                   // restage 2 ahead
    }
  }
  asm volatile("s_waitcnt vmcnt(0)" ::: "memory");
  __builtin_amdgcn_s_barrier();
  body(1);

  // epilogue: reduce l across quads, normalize, SEGMENT-ORDER store
  // (row = seg position; proj un-permutes via inv[]). 32B full sectors.
#pragma unroll
  for (int nq = 0; nq < 4; ++nq) {
    float l = lrun[nq];
    l += __shfl_xor(l, 16);
    l += __shfl_xor(l, 32);
    float inv_l = 1.f / l;
    int sout = q0 + nq * 16 + ml;
    size_t base = ((size_t)(b * 8192 + n * 512 + sout)) * 512 + h * 64;
#pragma unroll
    for (int dt = 0; dt < 4; ++dt) {
      svec4 pk;
#pragma unroll
      for (int g = 0; g < 4; ++g) pk[g] = f2bf(o[nq][dt][g] * inv_l);
      *(svec4*)(aout + base + dt * 16 + quad * 4) = pk;
    }
  }
}

// ---------------- Kernel 4: output projection (16384x512 @ 512x512^T) ------
// v5: A-row gather via inv[] (aout now segment-ordered). The 4 per-lane A
// row pointers are precomputed once per block (inv lookup is 4 L2-resident
// int loads); steady-state staging cost unchanged (global_load_lds source
// is per-lane; 8 lanes per row, rows were 1KB apart before too). Else = v4:
// counted-vmcnt 2-deep, 128x128 tile, BK=64, 4 waves 2x2.
__global__ __launch_bounds__(256, 2) void proj_kernel(
    const short* __restrict__ aout, const short* __restrict__ woutb,
    const int* __restrict__ inv, float* __restrict__ out) {
  __shared__ short As[2][128 * 64];
  __shared__ short Bs[2][128 * 64];
  int tid = threadIdx.x;
  int w = tid >> 6, lane = tid & 63;
  int ml = lane & 15, quad = lane >> 4;
  int rb = blockIdx.x & 127;
  int cb = blockIdx.x >> 7;
  int r0 = rb * 128, c0 = cb * 128;
  int wr = (w >> 1) * 64, wc = (w & 1) * 64;

  ffrag acc[4][4];
#pragma unroll
  for (int m = 0; m < 4; ++m)
#pragma unroll
    for (int n = 0; n < 4; ++n) acc[m][n] = (ffrag){0.f, 0.f, 0.f, 0.f};

  int scol = (lane & 7) * 8;  // tile col (shorts)
  // gather rows: output row grow -> stored row b*8192 + inv[grow&8191]
  const short* gAr[4];
#pragma unroll
  for (int i = 0; i < 4; ++i) {
    int grow = r0 + w * 32 + (lane >> 3) + i * 8;
    int prow = (grow & ~8191) | inv[grow & 8191];
    gAr[i] = aout + (size_t)prow * 512 + scol;
  }
  const short* gB = woutb + (size_t)(c0 + w * 32 + (lane >> 3)) * 512 + scol;

  auto stage = [&](int buf, int k0) {
#pragma unroll
    for (int i = 0; i < 4; ++i) {
      gload_lds16(gAr[i] + k0, (char*)&As[buf][0] + w * 4096 + i * 1024);
      gload_lds16(gB + (size_t)i * 8 * 512 + k0,
                  (char*)&Bs[buf][0] + w * 4096 + i * 1024);
    }
  };
  auto compute = [&](int buf) {
#pragma unroll
    for (int kk = 0; kk < 2; ++kk) {
      bfrag af[4], bf[4];
#pragma unroll
      for (int m = 0; m < 4; ++m)
        af[m] = *(const bfrag*)&As[buf][(wr + m * 16 + ml) * 64 + kk * 32 +
                                        quad * 8];
#pragma unroll
      for (int n = 0; n < 4; ++n)
        bf[n] = *(const bfrag*)&Bs[buf][(wc + n * 16 + ml) * 64 + kk * 32 +
                                        quad * 8];
#pragma unroll
      for (int m = 0; m < 4; ++m)
#pragma unroll
        for (int n = 0; n < 4; ++n)
          acc[m][n] = __builtin_amdgcn_mfma_f32_16x16x32_bf16(bf[n], af[m],
                                                              acc[m][n], 0, 0, 0);
    }
  };

  // counted-vmcnt pipeline, 2 tiles deep (8 k-tiles, k = t*64)
  stage(0, 0);
  stage(1, 64);
#pragma unroll 1
  for (int t = 0; t < 7; ++t) {
    asm volatile("s_waitcnt vmcnt(8)" ::: "memory");  // tile t landed
    __builtin_amdgcn_s_barrier();
    compute(t & 1);
    if (t < 6) {
      __builtin_amdgcn_s_barrier();
      stage(t & 1, (t + 2) * 64);
    }
  }
  asm volatile("s_waitcnt vmcnt(0)" ::: "memory");
  __builtin_amdgcn_s_barrier();
  compute(1);

#pragma unroll
  for (int m = 0; m < 4; ++m)
#pragma unroll
    for (int n = 0; n < 4; ++n)
      *(ffrag*)(out + (size_t)(r0 + wr + m * 16 + ml) * 512 + c0 + wc +
                n * 16 + quad * 4) = acc[m][n];
}

extern "C" void kernel_launch(void* const* d_in, const int* in_sizes, int n_in,
                              void* d_out, int out_size, void* d_ws,
                              size_t ws_size, hipStream_t stream) {
  const float* q = (const float*)d_in[0];
  const float* w_qkv = (const float*)d_in[3];
  const float* w_out = (const float*)d_in[4];
  float* out = (float*)d_out;

  char* ws = (char*)d_ws;
  int* perm = (int*)ws;                       //     32768 B
  short* xmean = (short*)(ws + 32768);        //   2097152 B
  short* weff = (short*)(ws + 2129920);       //    196608 B
  short* woutb = (short*)(ws + 2326528);      //    524288 B
  short* Qs = (short*)(ws + 2850816);         //  16777216 B
  short* Ks = (short*)(ws + 19628032);        //  16777216 B
  short* Vt = (short*)(ws + 36405248);        //  16777216 B
  short* aout = (short*)(ws + 53182464);      //  16777216 B
  int* inv = (int*)(ws + 69959680);           //     32768 B  (total ~70 MB)

  prep_kernel<<<5536, 256, 0, stream>>>(q, w_qkv, w_out, xmean, weff, woutb,
                                        perm, inv);
  qkv_kernel<<<1024, 256, 0, stream>>>(xmean, weff, perm, Qs, Ks, Vt);
  attn_kernel<<<512, 256, 0, stream>>>(Qs, Ks, Vt, perm, aout);
  proj_kernel<<<512, 256, 0, stream>>>(aout, woutb, inv, out);
}